// Round 1
// 711.983 us; speedup vs baseline: 1.3390x; 1.3390x over previous
//
#include <hip/hip_runtime.h>
#include <hip/hip_fp16.h>
#include <math.h>

// Reference: bev (1024,1,120,120) fp32 -> out (1024,120) fp32.
// R10 green @953us: VALU-saturated (VALUBusy~106%, conflicts ~6.6%, HBM ~0.4%).
// R11: the (a,s,t)->address/weight stream is IMAGE-INDEPENDENT, so process
// TWO images per block, packed per-pixel in one half2: H[y][x]=(imgA,imgB),
// zero-padded (padded coord = unpadded+1; pads at rows/cols 0,121,122 hold
// exact zeros). Per sample: ~12 instrs of shared address math + 2 ds_read2_b32
// (corners (0,1) and (123,124) off one address) + packed-fp16 x-lerp for both
// images + fp32 y-lerp/accum per image => ~13.5 VALU/sample/image vs ~21.
// Per-image arithmetic is bit-identical to R10 (fp16 x-lerp, fp32 y-lerp,
// same padded-clamp case analysis => same boundary semantics as reference).
#define NPIX  120
#define NS    120
#define NK    61             // independent bins 0..60; 61..119 mirrored
#define HSTR  123            // H cols: x = 0..122 (pads at 0, 121, 122)
#define HROWS 123            // H rows: y = 0..122 (pads at 0, 121, 122)
#define CHUNK 8              // angles in flight
#define NCHUNK 15            // 120 / 8
#define NT    960            // proven chassis: 8 angle-slots x 120, 15 waves

// LDS: 123*123*4 (60,516) + 8*120*8 (7,680) + 61*8 + 8 = 68,692 B.
// 2 blocks/CU on gfx950's 160 KiB => occupancy unchanged vs R10.

__global__ void ring_fused(const float* __restrict__ bev,
                           float* __restrict__ out,
                           int B) {
    __shared__ __half2 H[HROWS * HSTR];   // (imgA, imgB) packed padded image
    __shared__ float2 schunk[CHUNK * NS]; // 8 sinogram rows x 2 images
    __shared__ float2 outAcc[NK];
    __shared__ float2 invNorm;

    const int tid = threadIdx.x;          // 0..959
    const int b0  = blockIdx.x * 2;       // first image of the pair
    const int b1  = b0 + 1;
    const int al  = tid / NS;             // angle slot 0..7
    const int sk  = tid - al * NS;        // s (radon) / k (Goertzel, if <61)
    if (b0 >= B) return;

    // ---- stage: build H from both images (each word owned by 1 thread) -----
    const float* srcA = bev + (size_t)b0 * (NPIX * NPIX);
    const float* srcB = (b1 < B) ? bev + (size_t)b1 * (NPIX * NPIX) : srcA;
    for (int i = tid; i < HROWS * HSTR; i += NT) {
        int y = i / HSTR, x = i - y * HSTR;
        float va = 0.f, vb = 0.f;
        int gx = x - 1, gy = y - 1;
        if (gx >= 0 && gx < NPIX && gy >= 0 && gy < NPIX) {
            va = srcA[gy * NPIX + gx];
            vb = srcB[gy * NPIX + gx];
        }
        H[i] = __floats2half2_rn(va, vb);
    }
    __syncthreads();

    // ---- per-thread Goertzel constant (k = sk, used where sk < 61) ---------
    const float coef = 2.f * cosf((float)sk * 0.052359877559829887f);  // 2cos(pi k/60)
    const float sgn  = (sk & 1) ? -1.f : 1.f;
    const double STEP = 6.283185307179586 / 119.0;   // linspace(0,2pi,120) step
    float accKA = 0.f, accKB = 0.f;

    for (int ch = 0; ch < NCHUNK; ++ch) {
        // ---- radon: sinogram[a = ch*8+al][s = sk] for BOTH images ----------
        {
            int a = ch * CHUNK + al;
            float theta = (float)((double)a * STEP);
            float st = sinf(theta), ct = cosf(theta);
            float sf  = (float)sk - 59.5f;
            float Ax  = fmaf(sf, ct, 60.5f);   // padded px at tv=0
            float Ay  = fmaf(sf, st, 60.5f);   // padded py at tv=0
            float nst = -st;
            float aTA = 0.f, aDA = 0.f;        // img A: dual accumulators
            float aTB = 0.f, aDB = 0.f;        // img B
            float tv  = -59.5f;
            #pragma unroll 2
            for (int t = 0; t < NPIX; ++t) {
                float px = fmaf(tv, nst, Ax);
                float py = fmaf(tv, ct,  Ay);
                float cx = fminf(fmaxf(px, 0.f), 121.f);   // v_med3_f32
                float cy = fminf(fmaxf(py, 0.f), 121.f);
                float fx = floorf(cx), fy = floorf(cy);
                float wx = cx - fx,    wy = cy - fy;
                int   ai = (int)fmaf(fy, (float)HSTR, fx); // exact (<2^24)
                __half2 c00 = H[ai];                       // (A00,B00)
                __half2 c01 = H[ai + 1];                   // ds_read2_b32 pair 1
                __half2 c10 = H[ai + HSTR];                // (A10,B10)
                __half2 c11 = H[ai + HSTR + 1];            // ds_read2_b32 pair 2
                __half2 wx2 = __float2half2_rn(wx);
                __half2 th  = __hfma2(wx2, __hsub2(c01, c00), c00); // tops
                __half2 bh  = __hfma2(wx2, __hsub2(c11, c10), c10); // bottoms
                float2 tf = __half22float2(th);
                float2 bf = __half22float2(bh);
                aTA += tf.x;
                aDA  = fmaf(wy, bf.x - tf.x, aDA);
                aTB += tf.y;
                aDB  = fmaf(wy, bf.y - tf.y, aDB);
                tv += 1.f;
            }
            schunk[al * NS + sk] = make_float2(aTA + aDA, aTB + aDB);
        }
        __syncthreads();

        // ---- Goertzel: |F[k = sk]| of row al, both images (sk < 61) --------
        if (sk < NK) {
            const float2* row = schunk + al * NS;
            float u1a = 0.f, u2a = 0.f, u1b = 0.f, u2b = 0.f;
            #pragma unroll 4
            for (int s = 0; s < 60; ++s) {
                float2 lo = row[s];            // broadcast ds_read_b64
                float2 hi = row[s + 60];
                float wa = fmaf(sgn, hi.x, lo.x);
                float wb = fmaf(sgn, hi.y, lo.y);
                float va = fmaf(coef, u1a, wa - u2a); u2a = u1a; u1a = va;
                float vb = fmaf(coef, u1b, wb - u2b); u2b = u1b; u1b = vb;
            }
            float pa = fmaf(u1a, u1a, fmaf(u2a, u2a, -coef * u1a * u2a));
            float pb = fmaf(u1b, u1b, fmaf(u2b, u2b, -coef * u1b * u2b));
            pa = fmaxf(pa, 0.f);
            pb = fmaxf(pb, 0.f);
            accKA += sqrtf(fmaf(pa, (1.f / 120.f), 1e-15f));  // ortho + EPS_FFT
            accKB += sqrtf(fmaf(pb, (1.f / 120.f), 1e-15f));
        }
        __syncthreads();
    }

    // ---- reduce 8 angle-slot partials per bin (deterministic) --------------
    if (sk < NK) schunk[al * NS + sk] = make_float2(accKA, accKB);
    __syncthreads();
    if (tid < NK) {
        float sa = 0.f, sb = 0.f;
        for (int a2 = 0; a2 < CHUNK; ++a2) {
            float2 v = schunk[a2 * NS + tid];
            sa += v.x;
            sb += v.y;
        }
        outAcc[tid] = make_float2(sa, sb);
    }
    __syncthreads();

    // ---- L2 norm over the full mirrored 120-vector, one thread per image ---
    if (tid < 2) {
        float ssq = 0.f;
        for (int k = 0; k < NK; ++k) {
            float2 oa = outAcc[k];
            float v = tid ? oa.y : oa.x;
            float wgt = (k == 0 || k == 60) ? 1.f : 2.f;
            ssq = fmaf(wgt * v, v, ssq);
        }
        float inv = 1.f / fmaxf(sqrtf(ssq), 1e-12f);
        if (tid) invNorm.y = inv; else invNorm.x = inv;
    }
    __syncthreads();

    // ---- write fp32 output (Hermitian mirror), both images -----------------
    if (tid < 2 * NPIX) {
        int img = tid / NPIX;
        int j   = tid - img * NPIX;
        int k   = (j <= 60) ? j : (NPIX - j);
        int bb  = b0 + img;
        if (bb < B) {
            float2 oa = outAcc[k];
            float v = img ? (oa.y * invNorm.y) : (oa.x * invNorm.x);
            out[(size_t)bb * NPIX + j] = v;
        }
    }
}

extern "C" void kernel_launch(void* const* d_in, const int* in_sizes, int n_in,
                              void* d_out, int out_size, void* d_ws, size_t ws_size,
                              hipStream_t stream) {
    const float* bev = (const float*)d_in[0];
    float* out = (float*)d_out;
    int B = in_sizes[0] / (NPIX * NPIX);   // 1024
    int grid = (B + 1) / 2;                // 2 images per block
    hipLaunchKernelGGL(ring_fused, dim3(grid), dim3(NT), 0, stream, bev, out, B);
}